// Round 1
// baseline (426.155 us; speedup 1.0000x reference)
//
#include <hip/hip_runtime.h>
#include <stdint.h>
#include <stddef.h>

#define D_DIM 1024
#define T_LEN 4096
#define B_SZ 8
#define M_ROWS 32768   // B_SZ * T_LEN
#define KTOT 1024
#define CHUNK 128
#define NCHUNK 32      // T_LEN / CHUNK

typedef unsigned short u16;
typedef __bf16 bf16x8 __attribute__((ext_vector_type(8)));
typedef float f32x4 __attribute__((ext_vector_type(4)));

__device__ __forceinline__ u16 f2bf(float f) {
    union { float f; unsigned u; } v; v.f = f;
    unsigned r = v.u + 0x7fffu + ((v.u >> 16) & 1u);
    return (u16)(r >> 16);
}
__device__ __forceinline__ float bf2f(u16 h) {
    union { unsigned u; float f; } v; v.u = ((unsigned)h) << 16;
    return v.f;
}

// ---------------- f32 -> bf16 conversion (vectorized) ----------------
__global__ void convert_kernel(const float* __restrict__ src, u16* __restrict__ dst, int n4) {
    int i = blockIdx.x * blockDim.x + threadIdx.x;
    int stride = gridDim.x * blockDim.x;
    for (int j = i; j < n4; j += stride) {
        float4 v = ((const float4*)src)[j];
        ushort4 o;
        o.x = f2bf(v.x); o.y = f2bf(v.y); o.z = f2bf(v.z); o.w = f2bf(v.w);
        ((ushort4*)dst)[j] = o;
    }
}

// ---------------- async global->LDS, 16B per lane ----------------
__device__ __forceinline__ void gload16(const u16* g, u16* l) {
    __builtin_amdgcn_global_load_lds(
        (const __attribute__((address_space(1))) void*)g,
        (__attribute__((address_space(3))) void*)l,
        16, 0, 0);
}

// ---------------- GEMM: C[row,col] = sum_k A[row,k] * W[col,k] ----------------
// DUAL=true:  two B matrices (Wk, Wv); epilogue u = sigmoid(accK+bk)*(accV+bv) -> bf16 Uout
// DUAL=false: one B (Wq); epilogue out = (acc+bq)/mass -> f32 Fout
// Tile: BM=BN=128, BK=64. 4 waves (2x2), each 64x64. LDS swizzle: slot = kgrp ^ (row&7).
template<bool DUAL>
__global__ __launch_bounds__(256) void gemm_kernel(
    const u16* __restrict__ A,
    const u16* __restrict__ B0g,
    const u16* __restrict__ B1g,
    const float* __restrict__ bias0,
    const float* __restrict__ bias1,
    u16* __restrict__ Uout,
    float* __restrict__ Fout)
{
    extern __shared__ u16 smem[];
    u16* As  = smem;                 // [128][64]
    u16* Bs0 = smem + 128 * 64;
    u16* Bs1 = smem + 2 * 128 * 64;  // only used if DUAL

    const int tid  = threadIdx.x;
    const int w    = tid >> 6;
    const int lane = tid & 63;

    const int rowTile = blockIdx.x >> 3;
    const int colTile = blockIdx.x & 7;
    const int M0 = rowTile * 128;
    const int N0 = colTile * 128;

    // staging: each wave moves 32 rows of each tile via 4 x global_load_lds (8 rows / inst)
    const int lr = lane >> 3;   // row-within-8
    const int lg = lane & 7;    // stored 16B slot

    const u16* pA[4]; const u16* pB0[4]; const u16* pB1[4];
#pragma unroll
    for (int ii = 0; ii < 4; ++ii) {
        int r = (w * 4 + ii) * 8 + lr;
        int g = lg ^ (r & 7);   // fetch the logical k-group that belongs in stored slot lg
        pA[ii]  = A   + (size_t)(M0 + r) * KTOT + g * 8;
        pB0[ii] = B0g + (size_t)(N0 + r) * KTOT + g * 8;
        if (DUAL) pB1[ii] = B1g + (size_t)(N0 + r) * KTOT + g * 8;
    }

    const int wm = w >> 1;
    const int wn = w & 1;
    const int fr = lane & 15;
    const int fq = lane >> 4;

    f32x4 acc0[4][4] = {};
    f32x4 acc1[4][4] = {};

    for (int kt = 0; kt < KTOT / 64; ++kt) {
#pragma unroll
        for (int ii = 0; ii < 4; ++ii) {
            gload16(pA[ii],  As  + (w * 4 + ii) * 512);
            gload16(pB0[ii], Bs0 + (w * 4 + ii) * 512);
            if (DUAL) gload16(pB1[ii], Bs1 + (w * 4 + ii) * 512);
            pA[ii] += 64; pB0[ii] += 64; if (DUAL) pB1[ii] += 64;
        }
        __syncthreads();
#pragma unroll
        for (int kk = 0; kk < 2; ++kk) {
            const int kg = kk * 4 + fq;
            bf16x8 af[4], b0f[4], b1f[4];
#pragma unroll
            for (int m = 0; m < 4; ++m) {
                int row = wm * 64 + m * 16 + fr;
                af[m] = *(const bf16x8*)((const char*)As + row * 128 + ((kg ^ (row & 7)) << 4));
            }
#pragma unroll
            for (int n = 0; n < 4; ++n) {
                int row = wn * 64 + n * 16 + fr;
                int off = row * 128 + ((kg ^ (row & 7)) << 4);
                b0f[n] = *(const bf16x8*)((const char*)Bs0 + off);
                if (DUAL) b1f[n] = *(const bf16x8*)((const char*)Bs1 + off);
            }
#pragma unroll
            for (int m = 0; m < 4; ++m)
#pragma unroll
                for (int n = 0; n < 4; ++n) {
                    acc0[m][n] = __builtin_amdgcn_mfma_f32_16x16x32_bf16(af[m], b0f[n], acc0[m][n], 0, 0, 0);
                    if (DUAL)
                        acc1[m][n] = __builtin_amdgcn_mfma_f32_16x16x32_bf16(af[m], b1f[n], acc1[m][n], 0, 0, 0);
                }
        }
        __syncthreads();
    }

    // epilogue: C/D layout col=lane&15, row=(lane>>4)*4+reg
#pragma unroll
    for (int n = 0; n < 4; ++n) {
        int col = N0 + wn * 64 + n * 16 + fr;
        float b0 = bias0[col];
        float b1 = bias1[col];
#pragma unroll
        for (int m = 0; m < 4; ++m) {
            int row0 = M0 + wm * 64 + m * 16 + fq * 4;
#pragma unroll
            for (int j = 0; j < 4; ++j) {
                if (DUAL) {
                    float kl = acc0[m][n][j] + b0;
                    float vv = acc1[m][n][j] + b1;
                    float sg = 1.0f / (1.0f + __expf(-kl));
                    Uout[(size_t)(row0 + j) * D_DIM + col] = f2bf(sg * vv);
                } else {
                    Fout[(size_t)(row0 + j) * D_DIM + col] = (acc0[m][n][j] + b0) / b1;
                }
            }
        }
    }
}

// ---------------- scan pass A: per-chunk carry (from zero init) ----------------
__global__ void chunk_carry_kernel(const u16* __restrict__ u, const float* __restrict__ decay,
                                   float* __restrict__ localc) {
    int id = blockIdx.x * blockDim.x + threadIdx.x;   // B*NCHUNK*D = 262144
    int d = id & (D_DIM - 1);
    int c = (id >> 10) & (NCHUNK - 1);
    int b = id >> 15;
    float dec = decay[d];
    const u16* up = u + ((size_t)b * T_LEN + (size_t)c * CHUNK) * D_DIM + d;
    float carry = 0.f;
#pragma unroll 4
    for (int s = 0; s < CHUNK; ++s)
        carry = fmaf(carry, dec, bf2f(up[(size_t)s * D_DIM]));
    localc[id] = carry;
}

// ---------------- scan pass B: exclusive scan over chunk carries ----------------
__global__ void carry_scan_kernel(const float* __restrict__ localc, const float* __restrict__ state_p,
                                  const float* __restrict__ decay, float* __restrict__ prefix,
                                  float* __restrict__ final_p) {
    int id = blockIdx.x * blockDim.x + threadIdx.x;   // B*D = 8192
    int d = id & (D_DIM - 1);
    int b = id >> 10;
    float dec = decay[d];
    float dl = dec;
#pragma unroll
    for (int i = 0; i < 7; ++i) dl *= dl;             // dec^128
    float P = state_p[id];
    for (int c = 0; c < NCHUNK; ++c) {
        int idx = (b * NCHUNK + c) * D_DIM + d;
        prefix[idx] = P;
        P = fmaf(P, dl, localc[idx]);
    }
    final_p[id] = P;                                   // p after last timestep
}

// ---------------- scan pass C: reconstruct p in place (u -> p, bf16) ----------------
__global__ void reconstruct_kernel(u16* __restrict__ u, const float* __restrict__ decay,
                                   const float* __restrict__ prefix) {
    int id = blockIdx.x * blockDim.x + threadIdx.x;   // 262144
    int d = id & (D_DIM - 1);
    int c = (id >> 10) & (NCHUNK - 1);
    int b = id >> 15;
    float dec = decay[d];
    float p = prefix[id];
    u16* up = u + ((size_t)b * T_LEN + (size_t)c * CHUNK) * D_DIM + d;
#pragma unroll 4
    for (int s = 0; s < CHUNK; ++s) {
        p = fmaf(p, dec, bf2f(up[(size_t)s * D_DIM]));
        up[(size_t)s * D_DIM] = f2bf(p);
    }
}

extern "C" void kernel_launch(void* const* d_in, const int* in_sizes, int n_in,
                              void* d_out, int out_size, void* d_ws, size_t ws_size,
                              hipStream_t stream) {
    const float* x       = (const float*)d_in[0];
    const float* state_p = (const float*)d_in[1];
    const float* decay   = (const float*)d_in[2];
    const float* mass    = (const float*)d_in[3];
    const float* Wq      = (const float*)d_in[4];
    const float* bq      = (const float*)d_in[5];
    const float* Wk      = (const float*)d_in[6];
    const float* bk      = (const float*)d_in[7];
    const float* Wv      = (const float*)d_in[8];
    const float* bv      = (const float*)d_in[9];

    float* out     = (float*)d_out;
    float* final_p = out + (size_t)M_ROWS * D_DIM;

    // x_bf16 staged in d_out's first 64MB (dead before final GEMM overwrites it)
    u16* xb = (u16*)d_out;

    // workspace layout (~72MB)
    u16* wkb = (u16*)d_ws;
    u16* wvb = wkb + 1048576;
    u16* wqb = wvb + 1048576;
    u16* ub  = wqb + 1048576;                       // u then p in place, 64MB
    float* localc = (float*)(ub + (size_t)M_ROWS * D_DIM);
    float* prefix = localc + B_SZ * NCHUNK * D_DIM;

    convert_kernel<<<4096, 256, 0, stream>>>(x,  xb,  (M_ROWS * D_DIM) / 4);
    convert_kernel<<<1024, 256, 0, stream>>>(Wk, wkb, (D_DIM * D_DIM) / 4);
    convert_kernel<<<1024, 256, 0, stream>>>(Wv, wvb, (D_DIM * D_DIM) / 4);
    convert_kernel<<<1024, 256, 0, stream>>>(Wq, wqb, (D_DIM * D_DIM) / 4);

    // u = sigmoid(x Wk^T + bk) * (x Wv^T + bv)
    gemm_kernel<true><<<dim3(2048), dim3(256), 3 * 128 * 64 * 2, stream>>>(
        xb, wkb, wvb, bk, bv, ub, nullptr);

    chunk_carry_kernel<<<1024, 256, 0, stream>>>(ub, decay, localc);
    carry_scan_kernel<<<32, 256, 0, stream>>>(localc, state_p, decay, prefix, final_p);
    reconstruct_kernel<<<1024, 256, 0, stream>>>(ub, decay, prefix);

    // velocities = (p Wq^T + bq) / mass
    gemm_kernel<false><<<dim3(2048), dim3(256), 2 * 128 * 64 * 2, stream>>>(
        ub, wqb, nullptr, bq, mass, nullptr, out);
}

// Round 2
// 318.711 us; speedup vs baseline: 1.3371x; 1.3371x over previous
//
#include <hip/hip_runtime.h>
#include <stdint.h>
#include <stddef.h>

#define D_DIM 1024
#define T_LEN 4096
#define B_SZ 8
#define M_ROWS 32768   // B_SZ * T_LEN
#define KTOT 1024
#define CHUNK 128
#define NCHUNK 32      // T_LEN / CHUNK

typedef unsigned short u16;
typedef __bf16 bf16x8 __attribute__((ext_vector_type(8)));
typedef float f32x4 __attribute__((ext_vector_type(4)));

__device__ __forceinline__ u16 f2bf(float f) {
    union { float f; unsigned u; } v; v.f = f;
    unsigned r = v.u + 0x7fffu + ((v.u >> 16) & 1u);
    return (u16)(r >> 16);
}
__device__ __forceinline__ float bf2f(u16 h) {
    union { unsigned u; float f; } v; v.u = ((unsigned)h) << 16;
    return v.f;
}

// ---------------- f32 -> bf16 conversion (vectorized) ----------------
__global__ void convert_kernel(const float* __restrict__ src, u16* __restrict__ dst, int n4) {
    int i = blockIdx.x * blockDim.x + threadIdx.x;
    int stride = gridDim.x * blockDim.x;
    for (int j = i; j < n4; j += stride) {
        float4 v = ((const float4*)src)[j];
        ushort4 o;
        o.x = f2bf(v.x); o.y = f2bf(v.y); o.z = f2bf(v.z); o.w = f2bf(v.w);
        ((ushort4*)dst)[j] = o;
    }
}

// ---------------- async global->LDS, 16B per lane ----------------
__device__ __forceinline__ void gload16(const u16* g, u16* l) {
    __builtin_amdgcn_global_load_lds(
        (const __attribute__((address_space(1))) void*)g,
        (__attribute__((address_space(3))) void*)l,
        16, 0, 0);
}

// ---------------- pipelined GEMM: C[row,col] = sum_k A[row,k] * W[col,k] ----
// BK=32, 4 LDS buffers (32KB each, 128KB total), 3-deep counted-vmcnt pipeline,
// one s_barrier per K-step. 512 threads = 8 waves.
// DUAL:  BM=256, BN=128. wave grid 4x2, wave tile 64x64 per B matrix.
//        epilogue u = sigmoid(accK+bk)*(accV+bv) -> bf16 Uout
// single: BM=256, BN=256. wave grid 2x4, wave tile 128x64.
//        epilogue out = (acc+bq)/mass -> f32 Fout
template<bool DUAL>
__global__ __launch_bounds__(512, 2) void gemm2_kernel(
    const u16* __restrict__ A,
    const u16* __restrict__ B0g,
    const u16* __restrict__ B1g,
    const float* __restrict__ bias0,
    const float* __restrict__ bias1,
    u16* __restrict__ Uout,
    float* __restrict__ Fout)
{
    constexpr int BM = 256;
    constexpr int BN = DUAL ? 128 : 256;
    constexpr int MFR = DUAL ? 4 : 8;      // M fragments (16 rows each) per wave
    constexpr int BUF = 16384;             // u16 per buffer (32KB)
    constexpr int NT = KTOT / 32;          // 32 K-steps

    __shared__ u16 smem[4 * BUF];          // 128 KB static LDS

    const int tid  = threadIdx.x;
    const int w    = tid >> 6;
    const int lane = tid & 63;

    const int nCol = D_DIM / BN;           // 8 (dual) or 4 (single)
    const int M0 = (int)(blockIdx.x / nCol) * BM;
    const int N0 = (int)(blockIdx.x % nCol) * BN;

    // staging geometry: chunk = 16 rows x 32 cols bf16 (1KB). lane -> row=lane>>2, slot=lane&3.
    // LDS is written linearly (base + lane*16); global source is pre-swizzled so that
    // stored slot s holds k-group s ^ ((row>>1)&3).
    const int srow  = lane >> 2;
    const int sslot = lane & 3;
    const int sg    = sslot ^ ((srow >> 1) & 3);

    const u16* pA[2];
    const u16* pB0[2];
    const u16* pB1[1];
#pragma unroll
    for (int ii = 0; ii < 2; ++ii)
        pA[ii] = A + (size_t)(M0 + (w * 2 + ii) * 16 + srow) * KTOT + sg * 8;
    if (DUAL) {
        pB0[0] = B0g + (size_t)(N0 + w * 16 + srow) * KTOT + sg * 8;
        pB1[0] = B1g + (size_t)(N0 + w * 16 + srow) * KTOT + sg * 8;
    } else {
#pragma unroll
        for (int ii = 0; ii < 2; ++ii)
            pB0[ii] = B0g + (size_t)(N0 + (w * 2 + ii) * 16 + srow) * KTOT + sg * 8;
    }

    // stage one K-step tile (4 global_load_lds per wave) into buffer `buf`
    auto stage = [&](int buf) {
        u16* s = smem + buf * BUF;
#pragma unroll
        for (int ii = 0; ii < 2; ++ii) {
            gload16(pA[ii], s + (w * 2 + ii) * 512);
            pA[ii] += 32;
        }
        if (DUAL) {
            gload16(pB0[0], s + 8192 + w * 512);
            pB0[0] += 32;
            gload16(pB1[0], s + 12288 + w * 512);
            pB1[0] += 32;
        } else {
#pragma unroll
            for (int ii = 0; ii < 2; ++ii) {
                gload16(pB0[ii], s + 8192 + (w * 2 + ii) * 512);
                pB0[ii] += 32;
            }
        }
    };

    // wave tile position and fragment offsets
    const int wrow = DUAL ? (w >> 1) * 64 : (w >> 2) * 128;
    const int wcol = DUAL ? (w & 1) * 64 : (w & 3) * 64;
    const int fr = lane & 15;
    const int fq = lane >> 4;

    int offA[MFR], offB[4];
#pragma unroll
    for (int m = 0; m < MFR; ++m) {
        int row = wrow + m * 16 + fr;
        offA[m] = row * 32 + ((fq ^ ((row >> 1) & 3)) << 3);
    }
#pragma unroll
    for (int n = 0; n < 4; ++n) {
        int row = wcol + n * 16 + fr;
        offB[n] = row * 32 + ((fq ^ ((row >> 1) & 3)) << 3);
    }

    f32x4 acc0[MFR][4] = {};
    f32x4 acc1[MFR][4] = {};

    stage(0); stage(1); stage(2);   // 12 loads in flight

    for (int kt = 0; kt < NT; ++kt) {
        // wait only for the oldest stage (kt); keep 8 loads (2 stages) in flight
        if (kt < NT - 2)       asm volatile("s_waitcnt vmcnt(8)" ::: "memory");
        else if (kt == NT - 2) asm volatile("s_waitcnt vmcnt(4)" ::: "memory");
        else                   asm volatile("s_waitcnt vmcnt(0)" ::: "memory");
        __builtin_amdgcn_s_barrier();

        if (kt + 3 < NT) stage((kt + 3) & 3);

        const u16* As  = smem + (kt & 3) * BUF;
        const u16* Bs0 = As + 8192;
        const u16* Bs1 = As + 12288;

        bf16x8 af[MFR], b0f[4], b1f[4];
#pragma unroll
        for (int m = 0; m < MFR; ++m)
            af[m] = *(const bf16x8*)(As + offA[m]);
#pragma unroll
        for (int n = 0; n < 4; ++n) {
            b0f[n] = *(const bf16x8*)(Bs0 + offB[n]);
            if (DUAL) b1f[n] = *(const bf16x8*)(Bs1 + offB[n]);
        }
#pragma unroll
        for (int m = 0; m < MFR; ++m)
#pragma unroll
            for (int n = 0; n < 4; ++n) {
                acc0[m][n] = __builtin_amdgcn_mfma_f32_16x16x32_bf16(af[m], b0f[n], acc0[m][n], 0, 0, 0);
                if (DUAL)
                    acc1[m][n] = __builtin_amdgcn_mfma_f32_16x16x32_bf16(af[m], b1f[n], acc1[m][n], 0, 0, 0);
            }
    }

    // epilogue: C/D layout col=lane&15, row=(lane>>4)*4+reg
#pragma unroll
    for (int n = 0; n < 4; ++n) {
        int col = N0 + wcol + n * 16 + fr;
        float b0 = bias0[col];
        float b1 = bias1[col];
#pragma unroll
        for (int m = 0; m < MFR; ++m) {
            int row0 = M0 + wrow + m * 16 + fq * 4;
#pragma unroll
            for (int j = 0; j < 4; ++j) {
                if (DUAL) {
                    float kl = acc0[m][n][j] + b0;
                    float vv = acc1[m][n][j] + b1;
                    float sg2 = 1.0f / (1.0f + __expf(-kl));
                    Uout[(size_t)(row0 + j) * D_DIM + col] = f2bf(sg2 * vv);
                } else {
                    Fout[(size_t)(row0 + j) * D_DIM + col] = (acc0[m][n][j] + b0) / b1;
                }
            }
        }
    }
}

// ---------------- scan pass A: per-chunk carry (from zero init) ----------------
__global__ void chunk_carry_kernel(const u16* __restrict__ u, const float* __restrict__ decay,
                                   float* __restrict__ localc) {
    int id = blockIdx.x * blockDim.x + threadIdx.x;   // B*NCHUNK*D = 262144
    int d = id & (D_DIM - 1);
    int c = (id >> 10) & (NCHUNK - 1);
    int b = id >> 15;
    float dec = decay[d];
    const u16* up = u + ((size_t)b * T_LEN + (size_t)c * CHUNK) * D_DIM + d;
    float carry = 0.f;
#pragma unroll 4
    for (int s = 0; s < CHUNK; ++s)
        carry = fmaf(carry, dec, bf2f(up[(size_t)s * D_DIM]));
    localc[id] = carry;
}

// ---------------- scan pass B: exclusive scan over chunk carries ----------------
__global__ void carry_scan_kernel(const float* __restrict__ localc, const float* __restrict__ state_p,
                                  const float* __restrict__ decay, float* __restrict__ prefix,
                                  float* __restrict__ final_p) {
    int id = blockIdx.x * blockDim.x + threadIdx.x;   // B*D = 8192
    int d = id & (D_DIM - 1);
    int b = id >> 10;
    float dec = decay[d];
    float dl = dec;
#pragma unroll
    for (int i = 0; i < 7; ++i) dl *= dl;             // dec^128
    float P = state_p[id];
    for (int c = 0; c < NCHUNK; ++c) {
        int idx = (b * NCHUNK + c) * D_DIM + d;
        prefix[idx] = P;
        P = fmaf(P, dl, localc[idx]);
    }
    final_p[id] = P;                                   // p after last timestep
}

// ---------------- scan pass C: reconstruct p in place (u -> p, bf16) ----------------
__global__ void reconstruct_kernel(u16* __restrict__ u, const float* __restrict__ decay,
                                   const float* __restrict__ prefix) {
    int id = blockIdx.x * blockDim.x + threadIdx.x;   // 262144
    int d = id & (D_DIM - 1);
    int c = (id >> 10) & (NCHUNK - 1);
    int b = id >> 15;
    float dec = decay[d];
    float p = prefix[id];
    u16* up = u + ((size_t)b * T_LEN + (size_t)c * CHUNK) * D_DIM + d;
#pragma unroll 4
    for (int s = 0; s < CHUNK; ++s) {
        p = fmaf(p, dec, bf2f(up[(size_t)s * D_DIM]));
        up[(size_t)s * D_DIM] = f2bf(p);
    }
}

extern "C" void kernel_launch(void* const* d_in, const int* in_sizes, int n_in,
                              void* d_out, int out_size, void* d_ws, size_t ws_size,
                              hipStream_t stream) {
    const float* x       = (const float*)d_in[0];
    const float* state_p = (const float*)d_in[1];
    const float* decay   = (const float*)d_in[2];
    const float* mass    = (const float*)d_in[3];
    const float* Wq      = (const float*)d_in[4];
    const float* bq      = (const float*)d_in[5];
    const float* Wk      = (const float*)d_in[6];
    const float* bk      = (const float*)d_in[7];
    const float* Wv      = (const float*)d_in[8];
    const float* bv      = (const float*)d_in[9];

    float* out     = (float*)d_out;
    float* final_p = out + (size_t)M_ROWS * D_DIM;

    // x_bf16 staged in d_out's first 64MB (dead before final GEMM overwrites it)
    u16* xb = (u16*)d_out;

    // workspace layout (~72MB)
    u16* wkb = (u16*)d_ws;
    u16* wvb = wkb + 1048576;
    u16* wqb = wvb + 1048576;
    u16* ub  = wqb + 1048576;                       // u then p in place, 64MB
    float* localc = (float*)(ub + (size_t)M_ROWS * D_DIM);
    float* prefix = localc + B_SZ * NCHUNK * D_DIM;

    convert_kernel<<<4096, 256, 0, stream>>>(x,  xb,  (M_ROWS * D_DIM) / 4);
    convert_kernel<<<1024, 256, 0, stream>>>(Wk, wkb, (D_DIM * D_DIM) / 4);
    convert_kernel<<<1024, 256, 0, stream>>>(Wv, wvb, (D_DIM * D_DIM) / 4);
    convert_kernel<<<1024, 256, 0, stream>>>(Wq, wqb, (D_DIM * D_DIM) / 4);

    // u = sigmoid(x Wk^T + bk) * (x Wv^T + bv)
    gemm2_kernel<true><<<dim3(1024), dim3(512), 0, stream>>>(
        xb, wkb, wvb, bk, bv, ub, nullptr);

    chunk_carry_kernel<<<1024, 256, 0, stream>>>(ub, decay, localc);
    carry_scan_kernel<<<32, 256, 0, stream>>>(localc, state_p, decay, prefix, final_p);
    reconstruct_kernel<<<1024, 256, 0, stream>>>(ub, decay, prefix);

    // velocities = (p Wq^T + bq) / mass
    gemm2_kernel<false><<<dim3(512), dim3(512), 0, stream>>>(
        ub, wqb, nullptr, bq, mass, nullptr, out);
}

// Round 3
// 306.362 us; speedup vs baseline: 1.3910x; 1.0403x over previous
//
#include <hip/hip_runtime.h>
#include <stdint.h>
#include <stddef.h>

#define D_DIM 1024
#define T_LEN 4096
#define B_SZ 8
#define M_ROWS 32768   // B_SZ * T_LEN
#define KTOT 1024
#define CHUNK 64
#define NCHUNK 64      // T_LEN / CHUNK

typedef unsigned short u16;
typedef unsigned short u16x8 __attribute__((ext_vector_type(8)));
typedef __bf16 bf16x8 __attribute__((ext_vector_type(8)));
typedef float f32x4 __attribute__((ext_vector_type(4)));

__device__ __forceinline__ u16 f2bf(float f) {
    union { float f; unsigned u; } v; v.f = f;
    unsigned r = v.u + 0x7fffu + ((v.u >> 16) & 1u);
    return (u16)(r >> 16);
}
__device__ __forceinline__ float bf2f(u16 h) {
    union { unsigned u; float f; } v; v.u = ((unsigned)h) << 16;
    return v.f;
}

// ---------------- f32 -> bf16 conversion (vectorized) ----------------
__global__ void convert_kernel(const float* __restrict__ src, u16* __restrict__ dst, int n4) {
    int i = blockIdx.x * blockDim.x + threadIdx.x;
    int stride = gridDim.x * blockDim.x;
    for (int j = i; j < n4; j += stride) {
        float4 v = ((const float4*)src)[j];
        ushort4 o;
        o.x = f2bf(v.x); o.y = f2bf(v.y); o.z = f2bf(v.z); o.w = f2bf(v.w);
        ((ushort4*)dst)[j] = o;
    }
}

// three weight matrices in one launch
__global__ void convert3_kernel(const float* __restrict__ s0, const float* __restrict__ s1,
                                const float* __restrict__ s2,
                                u16* __restrict__ d0, u16* __restrict__ d1, u16* __restrict__ d2,
                                int n4each) {
    int i = blockIdx.x * blockDim.x + threadIdx.x;
    int total = 3 * n4each;
    int stride = gridDim.x * blockDim.x;
    for (int j = i; j < total; j += stride) {
        int which = j / n4each;
        int off = j - which * n4each;
        const float* s = which == 0 ? s0 : (which == 1 ? s1 : s2);
        u16* d = which == 0 ? d0 : (which == 1 ? d1 : d2);
        float4 v = ((const float4*)s)[off];
        ushort4 o;
        o.x = f2bf(v.x); o.y = f2bf(v.y); o.z = f2bf(v.z); o.w = f2bf(v.w);
        ((ushort4*)d)[off] = o;
    }
}

// ---------------- async global->LDS, 16B per lane ----------------
__device__ __forceinline__ void gload16(const u16* g, u16* l) {
    __builtin_amdgcn_global_load_lds(
        (const __attribute__((address_space(1))) void*)g,
        (__attribute__((address_space(3))) void*)l,
        16, 0, 0);
}

// ---------------- pipelined 2-phase GEMM: C[row,col] = sum_k A[row,k]*W[col,k]
// BK=32, 4 LDS buffers, 3-deep counted-vmcnt pipeline, 2 phases per K-step
// (phase = reads+stage / barrier / lgkmcnt / setprio MFMA), XCD-swizzled grid.
// DUAL:  BM=256,BN=128, wave 64x64 per B; epilogue u=sigmoid(accK+bk)*(accV+bv) -> bf16
// single:BM=256,BN=256, wave 128x64;    epilogue out=(acc+bq)/mass -> f32
template<bool DUAL>
__global__ __launch_bounds__(512, 2) void gemm3_kernel(
    const u16* __restrict__ A,
    const u16* __restrict__ B0g,
    const u16* __restrict__ B1g,
    const float* __restrict__ bias0,
    const float* __restrict__ bias1,
    u16* __restrict__ Uout,
    float* __restrict__ Fout)
{
    constexpr int BM = 256;
    constexpr int BN = DUAL ? 128 : 256;
    constexpr int MFR = DUAL ? 4 : 8;
    constexpr int BUF = 16384;             // u16 per buffer (32KB)
    constexpr int NT = KTOT / 32;          // 32 K-steps

    __shared__ u16 smem[4 * BUF];          // 128 KB

    const int tid  = threadIdx.x;
    const int w    = tid >> 6;
    const int lane = tid & 63;

    // XCD-aware swizzle: 8 XCDs, nwg % 8 == 0 (1024 or 512)
    const int cpx = gridDim.x >> 3;
    const int bid = blockIdx.x;
    const int swz = (bid & 7) * cpx + (bid >> 3);

    const int nCol = D_DIM / BN;           // 8 (dual) or 4 (single)
    const int M0 = (swz / nCol) * BM;
    const int N0 = (swz % nCol) * BM / (BM / BN);  // (swz % nCol) * BN

    // staging: chunk = 16 rows x 32 cols bf16 (1KB); lane -> row=lane>>2, slot=lane&3.
    // LDS written linearly; global src pre-swizzled: stored slot s holds kgrp s^((row>>1)&3).
    const int srow  = lane >> 2;
    const int sslot = lane & 3;
    const int sg    = sslot ^ ((srow >> 1) & 3);

    const u16* pA0 = A + (size_t)(M0 + (w * 2 + 0) * 16 + srow) * KTOT + sg * 8;
    const u16* pA1 = A + (size_t)(M0 + (w * 2 + 1) * 16 + srow) * KTOT + sg * 8;
    const u16* pB0a;
    const u16* pB0b = nullptr;
    const u16* pB1a = nullptr;
    if (DUAL) {
        pB0a = B0g + (size_t)(N0 + w * 16 + srow) * KTOT + sg * 8;
        pB1a = B1g + (size_t)(N0 + w * 16 + srow) * KTOT + sg * 8;
    } else {
        pB0a = B0g + (size_t)(N0 + (w * 2 + 0) * 16 + srow) * KTOT + sg * 8;
        pB0b = B0g + (size_t)(N0 + (w * 2 + 1) * 16 + srow) * KTOT + sg * 8;
    }

    auto stageA = [&](int buf) {
        u16* s = smem + buf * BUF;
        gload16(pA0, s + (w * 2 + 0) * 512); pA0 += 32;
        gload16(pA1, s + (w * 2 + 1) * 512); pA1 += 32;
    };
    auto stageB = [&](int buf) {
        u16* s = smem + buf * BUF;
        if (DUAL) {
            gload16(pB0a, s + 8192 + w * 512);  pB0a += 32;
            gload16(pB1a, s + 12288 + w * 512); pB1a += 32;
        } else {
            gload16(pB0a, s + 8192 + (w * 2 + 0) * 512); pB0a += 32;
            gload16(pB0b, s + 8192 + (w * 2 + 1) * 512); pB0b += 32;
        }
    };

    const int wrow = DUAL ? (w >> 1) * 64 : (w >> 2) * 128;
    const int wcol = DUAL ? (w & 1) * 64 : (w & 3) * 64;
    const int fr = lane & 15;
    const int fq = lane >> 4;

    int offA[MFR], offB[4];
#pragma unroll
    for (int m = 0; m < MFR; ++m) {
        int row = wrow + m * 16 + fr;
        offA[m] = row * 32 + ((fq ^ ((row >> 1) & 3)) << 3);
    }
#pragma unroll
    for (int n = 0; n < 4; ++n) {
        int row = wcol + n * 16 + fr;
        offB[n] = row * 32 + ((fq ^ ((row >> 1) & 3)) << 3);
    }

    f32x4 acc0[MFR][4] = {};
    f32x4 acc1[DUAL ? MFR : 1][4] = {};

    stageA(0); stageB(0); stageA(1); stageB(1); stageA(2); stageB(2);

    for (int kt = 0; kt < NT; ++kt) {
        if (kt < NT - 2)       asm volatile("s_waitcnt vmcnt(8)" ::: "memory");
        else if (kt == NT - 2) asm volatile("s_waitcnt vmcnt(4)" ::: "memory");
        else                   asm volatile("s_waitcnt vmcnt(0)" ::: "memory");
        __builtin_amdgcn_s_barrier();

        const u16* As  = smem + (kt & 3) * BUF;
        const u16* Bs0 = As + 8192;
        const u16* Bs1 = As + 12288;

        bf16x8 af[MFR], b0f[4], b1f[4];

        // ---------- phase A: af[0..3] + b0f reads, A-stage, MFMA cluster 0 ----------
#pragma unroll
        for (int m = 0; m < 4; ++m)
            af[m] = *(const bf16x8*)(As + offA[m]);
#pragma unroll
        for (int n = 0; n < 4; ++n)
            b0f[n] = *(const bf16x8*)(Bs0 + offB[n]);
        if (kt + 3 < NT) stageA((kt + 3) & 3);
        asm volatile("s_waitcnt lgkmcnt(0)" ::: "memory");
        __builtin_amdgcn_sched_barrier(0);
        __builtin_amdgcn_s_setprio(1);
#pragma unroll
        for (int m = 0; m < 4; ++m)
#pragma unroll
            for (int n = 0; n < 4; ++n)
                acc0[m][n] = __builtin_amdgcn_mfma_f32_16x16x32_bf16(af[m], b0f[n], acc0[m][n], 0, 0, 0);
        __builtin_amdgcn_s_setprio(0);
        __builtin_amdgcn_sched_barrier(0);

        // ---------- phase B: remaining reads, B-stage, MFMA cluster 1 ----------
        __builtin_amdgcn_s_barrier();
        if (DUAL) {
#pragma unroll
            for (int n = 0; n < 4; ++n)
                b1f[n] = *(const bf16x8*)(Bs1 + offB[n]);
        } else {
#pragma unroll
            for (int m = 4; m < MFR; ++m)
                af[m] = *(const bf16x8*)(As + offA[m]);
        }
        if (kt + 3 < NT) stageB((kt + 3) & 3);
        asm volatile("s_waitcnt lgkmcnt(0)" ::: "memory");
        __builtin_amdgcn_sched_barrier(0);
        __builtin_amdgcn_s_setprio(1);
        if (DUAL) {
#pragma unroll
            for (int m = 0; m < 4; ++m)
#pragma unroll
                for (int n = 0; n < 4; ++n)
                    acc1[m][n] = __builtin_amdgcn_mfma_f32_16x16x32_bf16(af[m], b1f[n], acc1[m][n], 0, 0, 0);
        } else {
#pragma unroll
            for (int m = 4; m < MFR; ++m)
#pragma unroll
                for (int n = 0; n < 4; ++n)
                    acc0[m][n] = __builtin_amdgcn_mfma_f32_16x16x32_bf16(af[m], b0f[n], acc0[m][n], 0, 0, 0);
        }
        __builtin_amdgcn_s_setprio(0);
        __builtin_amdgcn_sched_barrier(0);
    }

    // epilogue: C/D layout col=lane&15, row=(lane>>4)*4+reg
#pragma unroll
    for (int n = 0; n < 4; ++n) {
        int col = N0 + wcol + n * 16 + fr;
        float b0 = bias0[col];
        float b1 = bias1[col];
#pragma unroll
        for (int m = 0; m < MFR; ++m) {
            int row0 = M0 + wrow + m * 16 + fq * 4;
#pragma unroll
            for (int j = 0; j < 4; ++j) {
                if (DUAL) {
                    float kl = acc0[m][n][j] + b0;
                    float vv = acc1[m][n][j] + b1;
                    float sg2 = 1.0f / (1.0f + __expf(-kl));
                    Uout[(size_t)(row0 + j) * D_DIM + col] = f2bf(sg2 * vv);
                } else {
                    Fout[(size_t)(row0 + j) * D_DIM + col] = (acc0[m][n][j] + b0) / b1;
                }
            }
        }
    }
}

// ---------------- scan pass A: per-chunk carry (x8 vectorized) ----------------
__global__ void chunk_carry_kernel(const u16* __restrict__ u, const float* __restrict__ decay,
                                   float* __restrict__ localc) {
    int id = blockIdx.x * blockDim.x + threadIdx.x;   // B*NCHUNK*(D/8) = 65536
    int d8 = id & 127;
    int c  = (id >> 7) & (NCHUNK - 1);
    int b  = id >> 13;
    float4 dlo = ((const float4*)decay)[d8 * 2];
    float4 dhi = ((const float4*)decay)[d8 * 2 + 1];
    float dec[8] = {dlo.x, dlo.y, dlo.z, dlo.w, dhi.x, dhi.y, dhi.z, dhi.w};
    float carry[8] = {};
    const u16* up = u + ((size_t)b * T_LEN + (size_t)c * CHUNK) * D_DIM + d8 * 8;
    for (int s = 0; s < CHUNK; ++s) {
        u16x8 v = *(const u16x8*)(up + (size_t)s * D_DIM);
#pragma unroll
        for (int j = 0; j < 8; ++j)
            carry[j] = fmaf(carry[j], dec[j], bf2f(v[j]));
    }
    float* lc = localc + ((size_t)(b * NCHUNK + c)) * D_DIM + d8 * 8;
#pragma unroll
    for (int j = 0; j < 8; ++j) lc[j] = carry[j];
}

// ---------------- scan pass B: exclusive scan over chunk carries ----------------
__global__ void carry_scan_kernel(const float* __restrict__ localc, const float* __restrict__ state_p,
                                  const float* __restrict__ decay, float* __restrict__ prefix,
                                  float* __restrict__ final_p) {
    int id = blockIdx.x * blockDim.x + threadIdx.x;   // B*D = 8192
    int d = id & (D_DIM - 1);
    int b = id >> 10;
    float dec = decay[d];
    float dl = dec;
#pragma unroll
    for (int i = 0; i < 6; ++i) dl *= dl;             // dec^64
    float P = state_p[id];
    for (int c = 0; c < NCHUNK; ++c) {
        int idx = (b * NCHUNK + c) * D_DIM + d;
        prefix[idx] = P;
        P = fmaf(P, dl, localc[idx]);
    }
    final_p[id] = P;
}

// ---------------- scan pass C: reconstruct p in place (x8 vectorized) ----------------
__global__ void reconstruct_kernel(u16* __restrict__ u, const float* __restrict__ decay,
                                   const float* __restrict__ prefix) {
    int id = blockIdx.x * blockDim.x + threadIdx.x;   // 65536
    int d8 = id & 127;
    int c  = (id >> 7) & (NCHUNK - 1);
    int b  = id >> 13;
    float4 dlo = ((const float4*)decay)[d8 * 2];
    float4 dhi = ((const float4*)decay)[d8 * 2 + 1];
    float dec[8] = {dlo.x, dlo.y, dlo.z, dlo.w, dhi.x, dhi.y, dhi.z, dhi.w};
    const float* pf = prefix + ((size_t)(b * NCHUNK + c)) * D_DIM + d8 * 8;
    float p[8];
#pragma unroll
    for (int j = 0; j < 8; ++j) p[j] = pf[j];
    u16* up = u + ((size_t)b * T_LEN + (size_t)c * CHUNK) * D_DIM + d8 * 8;
    for (int s = 0; s < CHUNK; ++s) {
        u16x8 v = *(const u16x8*)(up + (size_t)s * D_DIM);
        u16x8 o;
#pragma unroll
        for (int j = 0; j < 8; ++j) {
            p[j] = fmaf(p[j], dec[j], bf2f(v[j]));
            o[j] = f2bf(p[j]);
        }
        *(u16x8*)(up + (size_t)s * D_DIM) = o;
    }
}

extern "C" void kernel_launch(void* const* d_in, const int* in_sizes, int n_in,
                              void* d_out, int out_size, void* d_ws, size_t ws_size,
                              hipStream_t stream) {
    const float* x       = (const float*)d_in[0];
    const float* state_p = (const float*)d_in[1];
    const float* decay   = (const float*)d_in[2];
    const float* mass    = (const float*)d_in[3];
    const float* Wq      = (const float*)d_in[4];
    const float* bq      = (const float*)d_in[5];
    const float* Wk      = (const float*)d_in[6];
    const float* bk      = (const float*)d_in[7];
    const float* Wv      = (const float*)d_in[8];
    const float* bv      = (const float*)d_in[9];

    float* out     = (float*)d_out;
    float* final_p = out + (size_t)M_ROWS * D_DIM;

    // x_bf16 staged in d_out's first 64MB (dead before final GEMM overwrites it)
    u16* xb = (u16*)d_out;

    // workspace layout (~74MB)
    u16* wkb = (u16*)d_ws;
    u16* wvb = wkb + 1048576;
    u16* wqb = wvb + 1048576;
    u16* ub  = wqb + 1048576;                       // u then p in place, 64MB
    float* localc = (float*)(ub + (size_t)M_ROWS * D_DIM);
    float* prefix = localc + B_SZ * NCHUNK * D_DIM;

    convert_kernel<<<4096, 256, 0, stream>>>(x, xb, (M_ROWS * D_DIM) / 4);
    convert3_kernel<<<1024, 256, 0, stream>>>(Wk, Wv, Wq, wkb, wvb, wqb, (D_DIM * D_DIM) / 4);

    // u = sigmoid(x Wk^T + bk) * (x Wv^T + bv)
    gemm3_kernel<true><<<dim3(1024), dim3(512), 0, stream>>>(
        xb, wkb, wvb, bk, bv, ub, nullptr);

    chunk_carry_kernel<<<256, 256, 0, stream>>>(ub, decay, localc);
    carry_scan_kernel<<<32, 256, 0, stream>>>(localc, state_p, decay, prefix, final_p);
    reconstruct_kernel<<<256, 256, 0, stream>>>(ub, decay, prefix);

    // velocities = (p Wq^T + bq) / mass
    gemm3_kernel<false><<<dim3(512), dim3(512), 0, stream>>>(
        ub, wqb, nullptr, bq, mass, nullptr, out);
}